// Round 8
// baseline (443.379 us; speedup 1.0000x reference)
//
#include <hip/hip_runtime.h>
#include <hip/hip_bf16.h>

#define N 8192
#define IN_F 512
#define OUT_F 64
#define S_SPLIT 16
#define JT (N / S_SPLIT)   // 512 columns per split
#define LOG2E 1.4426950408889634f

typedef __attribute__((ext_vector_type(8))) short short8;
typedef __attribute__((ext_vector_type(4))) float floatx4;
typedef __attribute__((ext_vector_type(4))) int intx4;
typedef unsigned long long ull;

__device__ inline short f2bf(float x) {
    __hip_bfloat16 b = __float2bfloat16(x);
    return __builtin_bit_cast(short, b);
}

// K1a: W [512][64] fp32 -> WT [64][512] bf16
__global__ void k_wt(const float* __restrict__ W, short* __restrict__ WT) {
    int idx = blockIdx.x * 256 + threadIdx.x;    // 32768 total
    int k = idx >> 6, f = idx & 63;
    WT[f * IN_F + k] = f2bf(W[k * OUT_F + f]);
}

// K1: WH = h @ W via bf16 MFMA. 512 blocks x 1 wave, 16 rows each.
// Epilogue: WHbT bf16 [64][8192] + wh1s/wh2s (= (WH·a)·log2e, pre-scaled).
__global__ __launch_bounds__(64) void k_wh(const float* __restrict__ h,
                                           const short* __restrict__ WT,
                                           const float* __restrict__ a,
                                           short* __restrict__ WHbT,
                                           float* __restrict__ wh1s,
                                           float* __restrict__ wh2s) {
    __shared__ float tile[OUT_F][17];
    int lane = threadIdx.x;
    int n = lane & 15, q = lane >> 4;
    int i0 = blockIdx.x * 16;
    int rowA = i0 + n;
    const float* hp = h + (size_t)rowA * IN_F + q * 8;
    floatx4 acc[4] = {};
    for (int k0 = 0; k0 < IN_F; k0 += 32) {
        floatx4 h0 = *(const floatx4*)(hp + k0);
        floatx4 h1 = *(const floatx4*)(hp + k0 + 4);
        short8 af;
#pragma unroll
        for (int j = 0; j < 4; j++) { af[j] = f2bf(h0[j]); af[j + 4] = f2bf(h1[j]); }
#pragma unroll
        for (int b = 0; b < 4; b++) {
            short8 bf_ = *(const short8*)(WT + (b * 16 + n) * IN_F + k0 + q * 8);
            acc[b] = __builtin_amdgcn_mfma_f32_16x16x32_bf16(af, bf_, acc[b], 0, 0, 0);
        }
    }
#pragma unroll
    for (int b = 0; b < 4; b++)
#pragma unroll
        for (int r = 0; r < 4; r++)
            tile[b * 16 + n][q * 4 + r] = acc[b][r];
    float a1v[4], a2v[4];
#pragma unroll
    for (int b = 0; b < 4; b++) { a1v[b] = a[b * 16 + n]; a2v[b] = a[OUT_F + b * 16 + n]; }
#pragma unroll
    for (int r = 0; r < 4; r++) {
        float s1 = 0.f, s2 = 0.f;
#pragma unroll
        for (int b = 0; b < 4; b++) { s1 += acc[b][r] * a1v[b]; s2 += acc[b][r] * a2v[b]; }
#pragma unroll
        for (int m = 1; m <= 8; m <<= 1) {
            s1 += __shfl_xor(s1, m, 64);
            s2 += __shfl_xor(s2, m, 64);
        }
        if (n == 0) {
            wh1s[i0 + q * 4 + r] = s1 * LOG2E;   // pre-scaled: exp(x)=2^(x*log2e)
            wh2s[i0 + q * 4 + r] = s2 * LOG2E;
        }
    }
    __syncthreads();
    const float* tc = tile[lane];
    short8 s0, s1v;
#pragma unroll
    for (int k = 0; k < 8; k++) { s0[k] = f2bf(tc[k]); s1v[k] = f2bf(tc[k + 8]); }
    *(short8*)(WHbT + (size_t)lane * N + i0) = s0;
    *(short8*)(WHbT + (size_t)lane * N + i0 + 8) = s1v;
}

// K2: fully fused, light waves. Wave = 16 rows x 512 cols.
// Phase 1: ballot-pack own 16 adjacency rows -> wave-private LDS strip.
// Phase 2: rolled 16-step masked-exp + MFMA; den via all-ones B-frag MFMA.
__global__ __launch_bounds__(256) void k_attn(const int* __restrict__ adj,
                                              const short* __restrict__ WHbT,
                                              const float* __restrict__ wh1s,
                                              const float* __restrict__ wh2s,
                                              float* __restrict__ num_part,
                                              float* __restrict__ den_part) {
    __shared__ unsigned ldsm[4 * 16 * 17];       // 4.25 KB: 4 waves x 16 rows x 16 dwords (+pad)
    int tid = threadIdx.x;
    int w = tid >> 6;
    int lane = tid & 63;
    int n = lane & 15, q = lane >> 4;
    int split = blockIdx.y;
    int j0 = split * JT;
    int i0 = (blockIdx.x * 4 + w) * 16;          // this wave's 16 rows
    unsigned* mym = ldsm + w * 16 * 17;

    // ---- phase 1: 16 rows x 512 cols -> bitmask (dword s covers cols j0+s*32)
    for (int r = 0; r < 16; r++) {
        const int* p = adj + (size_t)(i0 + r) * N + j0 + lane;
        ull m0 = __ballot(p[0]   > 0);
        ull m1 = __ballot(p[64]  > 0);
        ull m2 = __ballot(p[128] > 0);
        ull m3 = __ballot(p[192] > 0);
        ull m4 = __ballot(p[256] > 0);
        ull m5 = __ballot(p[320] > 0);
        ull m6 = __ballot(p[384] > 0);
        ull m7 = __ballot(p[448] > 0);
        if (lane < 16) {                          // lane d -> dword d (proven R5 swizzle)
            ull s0 = (lane & 2) ? m1 : m0;
            ull s1 = (lane & 2) ? m3 : m2;
            ull s2 = (lane & 2) ? m5 : m4;
            ull s3 = (lane & 2) ? m7 : m6;
            ull t0 = (lane & 4) ? s1 : s0;
            ull t1 = (lane & 4) ? s3 : s2;
            ull u  = (lane & 8) ? t1 : t0;
            unsigned dw = (lane & 1) ? (unsigned)(u >> 32) : (unsigned)u;
            mym[r * 17 + lane] = dw;
        }
    }
    // wave-private LDS region: in-wave lgkmcnt ordering suffices, no barrier

    // ---- phase 2
    float wh1f = wh1s[i0 + n];
    floatx4 acc[4] = {};
    floatx4 accd = {};                            // denominator via ones-MFMA
    const short* bp0 = WHbT + (size_t)n * N + j0 + q * 8;
    const float* w2p = wh2s + j0 + q * 8;
    int qs = q * 8;
    short8 ones;
#pragma unroll
    for (int k = 0; k < 8; k++) ones[k] = (short)0x3F80;   // bf16 1.0

    for (int s = 0; s < 16; s++) {
        short8 bfr[4];
#pragma unroll
        for (int b = 0; b < 4; b++)
            bfr[b] = *(const short8*)(bp0 + (size_t)b * 16 * N + s * 32);
        unsigned md = mym[n * 17 + s];
        floatx4 w20 = *(const floatx4*)(w2p + s * 32);
        floatx4 w21 = *(const floatx4*)(w2p + s * 32 + 4);

        short8 af;
#pragma unroll
        for (int jj = 0; jj < 8; jj++) {
            float x = wh1f + ((jj < 4) ? w20[jj] : w21[jj - 4]);  // already *log2e
            float t = fmaxf(x, 0.01f * x);                        // leaky_relu
            float e = __builtin_amdgcn_exp2f(t);                  // single v_exp_f32
            af[jj] = f2bf(((md >> (qs + jj)) & 1u) ? e : 0.f);
        }
#pragma unroll
        for (int b = 0; b < 4; b++)
            acc[b] = __builtin_amdgcn_mfma_f32_16x16x32_bf16(af, bfr[b], acc[b], 0, 0, 0);
        accd = __builtin_amdgcn_mfma_f32_16x16x32_bf16(af, ones, accd, 0, 0, 0);
    }

    // den: all cols of accd equal (B=ones); C/D row = q*4+r. Write from n==0.
    if (n == 0) {
#pragma unroll
        for (int r = 0; r < 4; r++)
            den_part[(size_t)split * N + i0 + q * 4 + r] = accd[r];
    }
    // num partials: row = q*4+r, col = b*16+n
    float* np_ = num_part + (size_t)split * N * OUT_F;
#pragma unroll
    for (int b = 0; b < 4; b++)
#pragma unroll
        for (int r = 0; r < 4; r++)
            np_[(size_t)(i0 + q * 4 + r) * OUT_F + b * 16 + n] = acc[b][r];
}

// K3: out = elu( (Σ num_part) / (Σ den_part) )
__global__ void k_final(const float* __restrict__ num_part,
                        const float* __restrict__ den_part,
                        float* __restrict__ out) {
    int idx = blockIdx.x * 256 + threadIdx.x;    // 524288 total
    int row = idx >> 6;
    float s = 0.f, d = 0.f;
#pragma unroll
    for (int sp = 0; sp < S_SPLIT; sp++) {
        s += num_part[(size_t)sp * N * OUT_F + idx];
        d += den_part[sp * N + row];
    }
    float x = s / d;
    out[idx] = (x > 0.f) ? x : (__expf(x) - 1.f);
}

extern "C" void kernel_launch(void* const* d_in, const int* in_sizes, int n_in,
                              void* d_out, int out_size, void* d_ws, size_t ws_size,
                              hipStream_t stream) {
    const float* h = (const float*)d_in[0];
    const int* adj = (const int*)d_in[1];
    const float* W = (const float*)d_in[2];
    const float* a = (const float*)d_in[3];
    float* out = (float*)d_out;

    char* ws = (char*)d_ws;
    short* WHbT  = (short*)(ws);                                  // 1 MB
    short* WT    = (short*)(ws + (size_t)(1 << 20));              // 64 KB
    float* wh1s  = (float*)(ws + (size_t)(1 << 20) + (64 << 10)); // 32 KB
    float* wh2s  = wh1s + N;                                      // 32 KB
    float* num_p = (float*)(ws + (size_t)(16 << 20));             // 32 MB
    float* den_p = (float*)(ws + (size_t)(48 << 20));             // 512 KB

    k_wt<<<dim3(128), dim3(256), 0, stream>>>(W, WT);
    k_wh<<<dim3(N / 16), dim3(64), 0, stream>>>(h, WT, a, WHbT, wh1s, wh2s);
    k_attn<<<dim3(N / 64, S_SPLIT), dim3(256), 0, stream>>>(adj, WHbT, wh1s, wh2s,
                                                            num_p, den_p);
    k_final<<<dim3((N * OUT_F) / 256), dim3(256), 0, stream>>>(num_p, den_p, out);
}

// Round 9
// 412.799 us; speedup vs baseline: 1.0741x; 1.0741x over previous
//
#include <hip/hip_runtime.h>
#include <hip/hip_bf16.h>

#define N 8192
#define IN_F 512
#define OUT_F 64
#define S_SPLIT 16
#define JT (N / S_SPLIT)   // 512 columns per split
#define LOG2E 1.4426950408889634f

typedef __attribute__((ext_vector_type(8))) short short8;
typedef __attribute__((ext_vector_type(4))) float floatx4;
typedef __attribute__((ext_vector_type(4))) int intx4;
typedef unsigned long long ull;

__device__ inline short f2bf(float x) {
    __hip_bfloat16 b = __float2bfloat16(x);
    return __builtin_bit_cast(short, b);
}

// K0: pack adjacency int32 {0,1} -> bitmask via ballot (proven R5 kernel).
// Wave wv covers flat elements [wv*512, wv*512+512); dword d of its 64B
// block covers elements wv*512 + d*32 .. +31 (row wv/16, split (wv%16)).
__global__ __launch_bounds__(256) void k_pack(const int* __restrict__ adj,
                                              unsigned* __restrict__ mask) {
    int wv = (blockIdx.x * 256 + threadIdx.x) >> 6;
    int lane = threadIdx.x & 63;
    const int* p = adj + (size_t)wv * 512 + lane;
    ull m0 = __ballot(p[0]   > 0);
    ull m1 = __ballot(p[64]  > 0);
    ull m2 = __ballot(p[128] > 0);
    ull m3 = __ballot(p[192] > 0);
    ull m4 = __ballot(p[256] > 0);
    ull m5 = __ballot(p[320] > 0);
    ull m6 = __ballot(p[384] > 0);
    ull m7 = __ballot(p[448] > 0);
    if (lane < 16) {
        ull s0 = (lane & 2) ? m1 : m0;
        ull s1 = (lane & 2) ? m3 : m2;
        ull s2 = (lane & 2) ? m5 : m4;
        ull s3 = (lane & 2) ? m7 : m6;
        ull t0 = (lane & 4) ? s1 : s0;
        ull t1 = (lane & 4) ? s3 : s2;
        ull u  = (lane & 8) ? t1 : t0;
        unsigned dw = (lane & 1) ? (unsigned)(u >> 32) : (unsigned)u;
        mask[wv * 16 + lane] = dw;
    }
}

// K1a: W [512][64] fp32 -> WT [64][512] bf16
__global__ void k_wt(const float* __restrict__ W, short* __restrict__ WT) {
    int idx = blockIdx.x * 256 + threadIdx.x;
    int k = idx >> 6, f = idx & 63;
    WT[f * IN_F + k] = f2bf(W[k * OUT_F + f]);
}

// K1: WH = h @ W via bf16 MFMA (R8-proven). WHbT bf16 [64][8192] + pre-scaled wh1s/wh2s.
__global__ __launch_bounds__(64) void k_wh(const float* __restrict__ h,
                                           const short* __restrict__ WT,
                                           const float* __restrict__ a,
                                           short* __restrict__ WHbT,
                                           float* __restrict__ wh1s,
                                           float* __restrict__ wh2s) {
    __shared__ float tile[OUT_F][17];
    int lane = threadIdx.x;
    int n = lane & 15, q = lane >> 4;
    int i0 = blockIdx.x * 16;
    int rowA = i0 + n;
    const float* hp = h + (size_t)rowA * IN_F + q * 8;
    floatx4 acc[4] = {};
    for (int k0 = 0; k0 < IN_F; k0 += 32) {
        floatx4 h0 = *(const floatx4*)(hp + k0);
        floatx4 h1 = *(const floatx4*)(hp + k0 + 4);
        short8 af;
#pragma unroll
        for (int j = 0; j < 4; j++) { af[j] = f2bf(h0[j]); af[j + 4] = f2bf(h1[j]); }
#pragma unroll
        for (int b = 0; b < 4; b++) {
            short8 bf_ = *(const short8*)(WT + (b * 16 + n) * IN_F + k0 + q * 8);
            acc[b] = __builtin_amdgcn_mfma_f32_16x16x32_bf16(af, bf_, acc[b], 0, 0, 0);
        }
    }
#pragma unroll
    for (int b = 0; b < 4; b++)
#pragma unroll
        for (int r = 0; r < 4; r++)
            tile[b * 16 + n][q * 4 + r] = acc[b][r];
    float a1v[4], a2v[4];
#pragma unroll
    for (int b = 0; b < 4; b++) { a1v[b] = a[b * 16 + n]; a2v[b] = a[OUT_F + b * 16 + n]; }
#pragma unroll
    for (int r = 0; r < 4; r++) {
        float s1 = 0.f, s2 = 0.f;
#pragma unroll
        for (int b = 0; b < 4; b++) { s1 += acc[b][r] * a1v[b]; s2 += acc[b][r] * a2v[b]; }
#pragma unroll
        for (int m = 1; m <= 8; m <<= 1) {
            s1 += __shfl_xor(s1, m, 64);
            s2 += __shfl_xor(s2, m, 64);
        }
        if (n == 0) {
            wh1s[i0 + q * 4 + r] = s1 * LOG2E;
            wh2s[i0 + q * 4 + r] = s2 * LOG2E;
        }
    }
    __syncthreads();
    const float* tc = tile[lane];
    short8 s0, s1v;
#pragma unroll
    for (int k = 0; k < 8; k++) { s0[k] = f2bf(tc[k]); s1v[k] = f2bf(tc[k + 8]); }
    *(short8*)(WHbT + (size_t)lane * N + i0) = s0;
    *(short8*)(WHbT + (size_t)lane * N + i0 + 8) = s1v;
}

// K1c: reshape WHbT -> BP (B-fragment-packed): for 32-col group g, feature
// block b, lane l=(n,q): BP[((g*4+b)*64+l)*8..+7] = WHbT[b*16+n][g*32+q*8..+7].
// Phase-2 B loads become base + lane*16 — perfectly coalesced.
__global__ __launch_bounds__(256) void k_bp(const short* __restrict__ WHbT,
                                            short* __restrict__ BP) {
    int g = blockIdx.x;                // 256 groups
    int b = threadIdx.x >> 6;          // 4 feature blocks
    int lane = threadIdx.x & 63;
    int n = lane & 15, q = lane >> 4;
    short8 v = *(const short8*)(WHbT + (size_t)(b * 16 + n) * N + g * 32 + q * 8);
    *(short8*)(BP + ((size_t)(g * 4 + b) * 64 + lane) * 8) = v;
}

// K2: masked-exp attention + (P @ WH) partials. rf=4 (wave owns 64 rows),
// no LDS; B-frags from BP (coalesced), mask from bitmask, den via ones-MFMA.
__global__ __launch_bounds__(256) void k_attn(const unsigned* __restrict__ maskb,
                                              const short* __restrict__ BP,
                                              const float* __restrict__ wh1s,
                                              const float* __restrict__ wh2s,
                                              float* __restrict__ num_part,
                                              float* __restrict__ den_part) {
    int tid = threadIdx.x;
    int w = tid >> 6;
    int lane = tid & 63;
    int n = lane & 15, q = lane >> 4, qs = q * 8;
    int split = blockIdx.y;
    int j0 = split * JT;
    int i0 = blockIdx.x * 256 + w * 64;

    float wh1f[4];
#pragma unroll
    for (int rf = 0; rf < 4; rf++) wh1f[rf] = wh1s[i0 + rf * 16 + n];

    floatx4 acc[4][4] = {};
    floatx4 accd[4] = {};
    const float* w2p = wh2s + j0 + qs;
    // BP as short8 array: index split*4096 + s*256 + b*64 + lane
    const short8* bp = (const short8*)BP + (size_t)split * 4096 + lane;
    short8 ones;
#pragma unroll
    for (int k = 0; k < 8; k++) ones[k] = (short)0x3F80;   // bf16 1.0

    intx4 mcur[4], mnxt[4];
#pragma unroll
    for (int rf = 0; rf < 4; rf++)
        mcur[rf] = *(const intx4*)(maskb + (size_t)(i0 + rf * 16 + n) * 256 + split * 16);

    for (int g = 0; g < 4; g++) {
        if (g < 3) {
#pragma unroll
            for (int rf = 0; rf < 4; rf++)
                mnxt[rf] = *(const intx4*)(maskb + (size_t)(i0 + rf * 16 + n) * 256
                                           + split * 16 + (g + 1) * 4);
        }
#pragma unroll
        for (int d = 0; d < 4; d++) {
            int s = g * 4 + d;
            short8 bfr[4];
#pragma unroll
            for (int b = 0; b < 4; b++)
                bfr[b] = bp[s * 256 + b * 64];          // coalesced 1KB block
            floatx4 w20 = *(const floatx4*)(w2p + s * 32);
            floatx4 w21 = *(const floatx4*)(w2p + s * 32 + 4);
#pragma unroll
            for (int rf = 0; rf < 4; rf++) {
                unsigned md = (unsigned)mcur[rf][d];
                short8 af;
#pragma unroll
                for (int jj = 0; jj < 8; jj++) {
                    float x = wh1f[rf] + ((jj < 4) ? w20[jj] : w21[jj - 4]);  // *log2e
                    float t = fmaxf(x, 0.01f * x);                            // leaky_relu
                    float e = __builtin_amdgcn_exp2f(t);
                    af[jj] = f2bf(((md >> (qs + jj)) & 1u) ? e : 0.f);
                }
#pragma unroll
                for (int b = 0; b < 4; b++)
                    acc[rf][b] = __builtin_amdgcn_mfma_f32_16x16x32_bf16(af, bfr[b], acc[rf][b], 0, 0, 0);
                accd[rf] = __builtin_amdgcn_mfma_f32_16x16x32_bf16(af, ones, accd[rf], 0, 0, 0);
            }
        }
#pragma unroll
        for (int rf = 0; rf < 4; rf++) mcur[rf] = mnxt[rf];
    }

    // den (all cols of accd equal): C/D row = q*4+r
#pragma unroll
    for (int rf = 0; rf < 4; rf++) {
        if (n == 0) {
#pragma unroll
            for (int r = 0; r < 4; r++)
                den_part[(size_t)split * N + i0 + rf * 16 + q * 4 + r] = accd[rf][r];
        }
    }
    // num: row = q*4+r, col = b*16+n
    float* np_ = num_part + (size_t)split * N * OUT_F;
#pragma unroll
    for (int rf = 0; rf < 4; rf++)
#pragma unroll
        for (int b = 0; b < 4; b++)
#pragma unroll
            for (int r = 0; r < 4; r++)
                np_[(size_t)(i0 + rf * 16 + q * 4 + r) * OUT_F + b * 16 + n] = acc[rf][b][r];
}

// K3: out = elu( (Σ num_part) / (Σ den_part) )
__global__ void k_final(const float* __restrict__ num_part,
                        const float* __restrict__ den_part,
                        float* __restrict__ out) {
    int idx = blockIdx.x * 256 + threadIdx.x;
    int row = idx >> 6;
    float s = 0.f, d = 0.f;
#pragma unroll
    for (int sp = 0; sp < S_SPLIT; sp++) {
        s += num_part[(size_t)sp * N * OUT_F + idx];
        d += den_part[sp * N + row];
    }
    float x = s / d;
    out[idx] = (x > 0.f) ? x : (__expf(x) - 1.f);
}

extern "C" void kernel_launch(void* const* d_in, const int* in_sizes, int n_in,
                              void* d_out, int out_size, void* d_ws, size_t ws_size,
                              hipStream_t stream) {
    const float* h = (const float*)d_in[0];
    const int* adj = (const int*)d_in[1];
    const float* W = (const float*)d_in[2];
    const float* a = (const float*)d_in[3];
    float* out = (float*)d_out;

    char* ws = (char*)d_ws;
    short* WHbT     = (short*)(ws);                                  // 1 MB
    short* WT       = (short*)(ws + (size_t)(1 << 20));              // 64 KB
    float* wh1s     = (float*)(ws + (size_t)(1 << 20) + (64 << 10)); // 32 KB
    float* wh2s     = wh1s + N;                                      // 32 KB
    unsigned* maskb = (unsigned*)(ws + (size_t)(2 << 20));           // 8 MB
    short* BP       = (short*)(ws + (size_t)(12 << 20));             // 1 MB
    float* num_p    = (float*)(ws + (size_t)(16 << 20));             // 32 MB
    float* den_p    = (float*)(ws + (size_t)(48 << 20));             // 512 KB

    k_pack<<<dim3((N / 32) * (N / 256) * 4), dim3(256), 0, stream>>>(adj, maskb);
    k_wt<<<dim3(128), dim3(256), 0, stream>>>(W, WT);
    k_wh<<<dim3(N / 16), dim3(64), 0, stream>>>(h, WT, a, WHbT, wh1s, wh2s);
    k_bp<<<dim3(256), dim3(256), 0, stream>>>(WHbT, BP);
    k_attn<<<dim3(N / 256, S_SPLIT), dim3(256), 0, stream>>>(maskb, BP, wh1s, wh2s,
                                                             num_p, den_p);
    k_final<<<dim3((N * OUT_F) / 256), dim3(256), 0, stream>>>(num_p, den_p, out);
}